// Round 1
// baseline (9008.353 us; speedup 1.0000x reference)
//
#include <hip/hip_runtime.h>
#include <math.h>

// Problem constants
#define B_   32
#define S_   32
#define N_   512
#define D_   16
#define H_   64
#define D1_  128          // 2*H
#define EPS_ 1e-5f
#define BD1_ 4096         // B*D1
#define BD2_ 2048         // B*H
#define CNT_ 16384.0f     // B*N samples for batchnorm

__device__ __forceinline__ float sigm(float x) { return 1.0f / (1.0f + __expf(-x)); }

// ---------------------------------------------------------------------------
// Degree/scaling factors from incidence matrix H (512x128):
//   dv[n] = row sums, de[e] = col sums
//   Hs[n][e] = H/sqrt(dv[n]);  Hd[n][e] = Hs[n][e]/de[e]
// Then G = Hd @ Hs^T (built by a gemm call).
// ---------------------------------------------------------------------------
__global__ __launch_bounds__(256) void k_deg(const float* __restrict__ Hm,
                                             float* __restrict__ Hs,
                                             float* __restrict__ Hd) {
  __shared__ float sdv[512];
  __shared__ float sde[128];
  __shared__ float tmp[256];
  const int tid = threadIdx.x;
  // column sums (each thread: one e, half the rows)
  const int e = tid & 127, half = tid >> 7;
  float p = 0.f;
  for (int r = 0; r < 256; ++r) p += Hm[(half * 256 + r) * 128 + e];
  tmp[tid] = p;
  // row sums (rows tid, tid+256)
  for (int n = tid; n < 512; n += 256) {
    float s = 0.f;
    for (int k = 0; k < 128; k += 4) {
      float4 v = *(const float4*)&Hm[n * 128 + k];
      s += v.x + v.y + v.z + v.w;
    }
    sdv[n] = s;
  }
  __syncthreads();
  if (tid < 128) sde[tid] = tmp[tid] + tmp[tid + 128];
  __syncthreads();
  for (int i = tid; i < 512 * 128; i += 256) {
    int n = i >> 7, ee = i & 127;
    float hv = Hm[i];
    float hs = hv * rsqrtf(sdv[n]);
    Hs[i] = hs;
    Hd[i] = hs / sde[ee];
  }
}

// ---------------------------------------------------------------------------
// Generic fp32 tiled GEMM:  C(MxN) = A(MxK) @ B, row-major.
// TRB=true: B stored as (N x K) row-major (i.e. we use B^T).
// SMODE: 0 none; 1: per-column channel = (globalcol & chmask) sum/sumsq atomics;
//        2: out-layer channels ch = ((col>>6)&1)*2 + (col&1).
// zptr/zn: block(0,0) zeroes zn floats at zptr (stats buffer for a LATER kernel).
// ---------------------------------------------------------------------------
template <int BM, int BN, int TM, int TN, int SMODE, bool TRB>
__global__ __launch_bounds__(256) void gemmk(
    const float* __restrict__ A, const float* __restrict__ B, float* __restrict__ C,
    int M, int N, int K, int chmask, float* __restrict__ stats, int statsCH,
    float* __restrict__ zptr, int zn) {
  constexpr int KT = 16;
  __shared__ float As[KT][BM];
  __shared__ float Bs[KT][BN];
  const int tid = threadIdx.x;
  if (zptr && blockIdx.x == 0 && blockIdx.y == 0 && tid < zn) zptr[tid] = 0.f;
  constexpr int NTX = BN / TN;
  const int tx = tid % NTX;
  const int ty = tid / NTX;
  const int n0 = blockIdx.x * BN;
  const int m0 = blockIdx.y * BM;
  float acc[TM][TN];
#pragma unroll
  for (int i = 0; i < TM; ++i)
#pragma unroll
    for (int j = 0; j < TN; ++j) acc[i][j] = 0.f;

  const int ra = tid >> 2;            // transposed-tile load: row
  const int ca = (tid & 3) * 4;       // k offset (float4)
  constexpr int TPRB = BN / 4;
  const int kb = tid / TPRB;
  const int cb = (tid % TPRB) * 4;

  for (int k0 = 0; k0 < K; k0 += KT) {
    if (ra < BM) {
      float4 v = *(const float4*)&A[(size_t)(m0 + ra) * K + k0 + ca];
      As[ca + 0][ra] = v.x; As[ca + 1][ra] = v.y;
      As[ca + 2][ra] = v.z; As[ca + 3][ra] = v.w;
    }
    if (TRB) {
      if (ra < BN) {
        float4 v = *(const float4*)&B[(size_t)(n0 + ra) * K + k0 + ca];
        Bs[ca + 0][ra] = v.x; Bs[ca + 1][ra] = v.y;
        Bs[ca + 2][ra] = v.z; Bs[ca + 3][ra] = v.w;
      }
    } else {
      if (kb < KT) {
        *(float4*)&Bs[kb][cb] = *(const float4*)&B[(size_t)(k0 + kb) * N + n0 + cb];
      }
    }
    __syncthreads();
#pragma unroll
    for (int kk = 0; kk < KT; ++kk) {
      float a[TM], bv[TN];
#pragma unroll
      for (int i = 0; i < TM; ++i) a[i] = As[kk][ty * TM + i];
#pragma unroll
      for (int j = 0; j < TN; ++j) bv[j] = Bs[kk][tx * TN + j];
#pragma unroll
      for (int i = 0; i < TM; ++i)
#pragma unroll
        for (int j = 0; j < TN; ++j) acc[i][j] = fmaf(a[i], bv[j], acc[i][j]);
    }
    __syncthreads();
  }
#pragma unroll
  for (int i = 0; i < TM; ++i)
#pragma unroll
    for (int j = 0; j < TN; ++j)
      C[(size_t)(m0 + ty * TM + i) * N + n0 + tx * TN + j] = acc[i][j];

  if (SMODE > 0) {
    float* red1 = &As[0][0];
    float* red2 = &Bs[0][0];
    float cs[TN], cq[TN];
#pragma unroll
    for (int j = 0; j < TN; ++j) {
      float s = 0.f, q = 0.f;
#pragma unroll
      for (int i = 0; i < TM; ++i) { s += acc[i][j]; q = fmaf(acc[i][j], acc[i][j], q); }
      cs[j] = s; cq[j] = q;
    }
    // LDS is free to reuse (main loop ended with __syncthreads)
#pragma unroll
    for (int j = 0; j < TN; ++j) {
      red1[ty * BN + tx * TN + j] = cs[j];
      red2[ty * BN + tx * TN + j] = cq[j];
    }
    __syncthreads();
    if (tid < BN) {
      float s = 0.f, q = 0.f;
      constexpr int NTY = BM / TM;
      for (int r2 = 0; r2 < NTY; ++r2) { s += red1[r2 * BN + tid]; q += red2[r2 * BN + tid]; }
      int gc = n0 + tid;
      int ch = (SMODE == 1) ? (gc & chmask) : (((gc >> 6) & 1) * 2 + (gc & 1));
      atomicAdd(&stats[ch], s);
      atomicAdd(&stats[statsCH + ch], q);
    }
  }
}

// ---------------------------------------------------------------------------
// X1t[(m*32+b)*128 + d] = sum_k cat(x_t, h)[b,m,k] * W1[k,d]   (K=80, N=128)
// ---------------------------------------------------------------------------
__global__ __launch_bounds__(256) void xw_cat1(
    const float* __restrict__ inp, const float* __restrict__ h,
    const float* __restrict__ W, float* __restrict__ Xout, int t,
    float* __restrict__ zptr, int zn) {
  __shared__ float As[80][64];
  __shared__ float Ws[80][128];
  const int tid = threadIdx.x;
  if (blockIdx.x == 0 && tid < zn) zptr[tid] = 0.f;
  for (int i = tid * 4; i < 80 * 128; i += 1024)
    *(float4*)(((float*)Ws) + i) = *(const float4*)&W[i];
  const int rl = tid >> 2;
  const int r = blockIdx.x * 64 + rl;
  const int m = r >> 5, b = r & 31;
  const int k4 = (tid & 3) * 4;
  {
    float4 v = *(const float4*)&inp[(size_t)((b * S_ + t) * N_ + m) * D_ + k4];
    As[k4 + 0][rl] = v.x; As[k4 + 1][rl] = v.y; As[k4 + 2][rl] = v.z; As[k4 + 3][rl] = v.w;
  }
#pragma unroll
  for (int q = 0; q < 4; ++q) {
    int c = (tid & 3) * 16 + q * 4;
    float4 v = *(const float4*)&h[(size_t)(b * N_ + m) * H_ + c];
    As[16 + c + 0][rl] = v.x; As[16 + c + 1][rl] = v.y;
    As[16 + c + 2][rl] = v.z; As[16 + c + 3][rl] = v.w;
  }
  __syncthreads();
  const int tx = tid & 15, ty = tid >> 4;
  float acc[4][8];
#pragma unroll
  for (int i = 0; i < 4; ++i)
#pragma unroll
    for (int j = 0; j < 8; ++j) acc[i][j] = 0.f;
  for (int k = 0; k < 80; ++k) {
    float a[4], bv[8];
#pragma unroll
    for (int i = 0; i < 4; ++i) a[i] = As[k][ty * 4 + i];
#pragma unroll
    for (int j = 0; j < 8; ++j) bv[j] = Ws[k][tx * 8 + j];
#pragma unroll
    for (int i = 0; i < 4; ++i)
#pragma unroll
      for (int j = 0; j < 8; ++j) acc[i][j] = fmaf(a[i], bv[j], acc[i][j]);
  }
#pragma unroll
  for (int i = 0; i < 4; ++i)
#pragma unroll
    for (int j = 0; j < 8; ++j)
      Xout[(size_t)(blockIdx.x * 64 + ty * 4 + i) * D1_ + tx * 8 + j] = acc[i][j];
}

// ---------------------------------------------------------------------------
// X2t = cat(x_t, r*h) @ W2, with r = sigmoid(gconv1-out) computed on the fly.
// Flat split semantics: conc flat index j (<32768) -> node j>>7, channel j&127.
// ---------------------------------------------------------------------------
__global__ __launch_bounds__(256) void xw_cat2(
    const float* __restrict__ inp, const float* __restrict__ h,
    const float* __restrict__ W, float* __restrict__ Xout,
    const float* __restrict__ G1t, const float* __restrict__ X1t,
    const float* __restrict__ st1, const float* __restrict__ gamma1,
    const float* __restrict__ beta1, const float* __restrict__ bias1,
    int t, float* __restrict__ zptr, int zn) {
  __shared__ float As[80][64];
  __shared__ float Ws[80][64];
  __shared__ float sm[128], sa[128], sb[128], sbb[128];
  const int tid = threadIdx.x;
  if (blockIdx.x == 0 && tid < zn) zptr[tid] = 0.f;
  if (tid < 128) {
    float mean = st1[tid] * (1.f / CNT_);
    float var = fmaf(st1[128 + tid], 1.f / CNT_, -mean * mean);
    float inv = rsqrtf(var + EPS_);
    sm[tid] = mean; sa[tid] = inv * gamma1[tid];
    sb[tid] = beta1[tid]; sbb[tid] = bias1[tid];
  }
  __syncthreads();
  for (int i = tid * 4; i < 80 * 64; i += 1024)
    *(float4*)(((float*)Ws) + i) = *(const float4*)&W[i];
  const int rl = tid >> 2;
  const int r = blockIdx.x * 64 + rl;
  const int m = r >> 5, b = r & 31;
  const int k4 = (tid & 3) * 4;
  {
    float4 v = *(const float4*)&inp[(size_t)((b * S_ + t) * N_ + m) * D_ + k4];
    As[k4 + 0][rl] = v.x; As[k4 + 1][rl] = v.y; As[k4 + 2][rl] = v.z; As[k4 + 3][rl] = v.w;
  }
#pragma unroll
  for (int q = 0; q < 4; ++q) {
    int c = (tid & 3) * 16 + q * 4;
    float4 hv = *(const float4*)&h[(size_t)(b * N_ + m) * H_ + c];
    int j0 = m * H_ + c;
    int n = j0 >> 7;
    int dd = j0 & 127;
    float4 gv = *(const float4*)&G1t[(size_t)n * BD1_ + b * D1_ + dd];
    float4 xv = *(const float4*)&X1t[((size_t)n * 32 + b) * D1_ + dd];
    float hva[4] = {hv.x, hv.y, hv.z, hv.w};
    float gva[4] = {gv.x, gv.y, gv.z, gv.w};
    float xva[4] = {xv.x, xv.y, xv.z, xv.w};
#pragma unroll
    for (int i2 = 0; i2 < 4; ++i2) {
      int d2 = dd + i2;
      float pre = fmaf(gva[i2] - sm[d2], sa[d2], sb[d2]);
      pre = fmaxf(pre, 0.f) + xva[i2] + sbb[d2];
      As[16 + c + i2][rl] = sigm(pre) * hva[i2];
    }
  }
  __syncthreads();
  const int tx = tid & 15, ty = tid >> 4;
  float acc[4][4];
#pragma unroll
  for (int i = 0; i < 4; ++i)
#pragma unroll
    for (int j = 0; j < 4; ++j) acc[i][j] = 0.f;
  for (int k = 0; k < 80; ++k) {
    float a[4], bv[4];
#pragma unroll
    for (int i = 0; i < 4; ++i) a[i] = As[k][ty * 4 + i];
#pragma unroll
    for (int j = 0; j < 4; ++j) bv[j] = Ws[k][tx * 4 + j];
#pragma unroll
    for (int i = 0; i < 4; ++i)
#pragma unroll
      for (int j = 0; j < 4; ++j) acc[i][j] = fmaf(a[i], bv[j], acc[i][j]);
  }
#pragma unroll
  for (int i = 0; i < 4; ++i)
#pragma unroll
    for (int j = 0; j < 4; ++j)
      Xout[(size_t)(blockIdx.x * 64 + ty * 4 + i) * H_ + tx * 4 + j] = acc[i][j];
}

// ---------------------------------------------------------------------------
// u (from gconv1 nodes 256..511) + c = tanh(gconv2 out) + h update.
// h layout (b,m,c) flat == idx. Optionally writes feats1[t] into out feats region.
// ---------------------------------------------------------------------------
__global__ __launch_bounds__(256) void elt2k(
    const float* __restrict__ G1t, const float* __restrict__ X1t, const float* __restrict__ st1,
    const float* __restrict__ gamma1, const float* __restrict__ beta1, const float* __restrict__ bias1,
    const float* __restrict__ G2t, const float* __restrict__ X2t, const float* __restrict__ st2,
    const float* __restrict__ gamma2, const float* __restrict__ beta2, const float* __restrict__ bias2,
    float* __restrict__ h, float* __restrict__ out1, int t, int writeFeats) {
  const int idx = (blockIdx.x * 256 + threadIdx.x) * 4;
  const int b = idx >> 15;
  const int rem = idx & 32767;
  const int m = rem >> 6, c0 = rem & 63;
  const int nu = 256 + (rem >> 7);
  const int ddu = rem & 127;
  float4 g1v = *(const float4*)&G1t[(size_t)nu * BD1_ + b * D1_ + ddu];
  float4 x1v = *(const float4*)&X1t[((size_t)nu * 32 + b) * D1_ + ddu];
  float4 g2v = *(const float4*)&G2t[(size_t)m * BD2_ + b * H_ + c0];
  float4 x2v = *(const float4*)&X2t[((size_t)m * 32 + b) * H_ + c0];
  float4 hv = *(const float4*)&h[idx];
  float g1a[4] = {g1v.x, g1v.y, g1v.z, g1v.w};
  float x1a[4] = {x1v.x, x1v.y, x1v.z, x1v.w};
  float g2a[4] = {g2v.x, g2v.y, g2v.z, g2v.w};
  float x2a[4] = {x2v.x, x2v.y, x2v.z, x2v.w};
  float ha[4] = {hv.x, hv.y, hv.z, hv.w};
  float hn[4];
#pragma unroll
  for (int i = 0; i < 4; ++i) {
    int du = ddu + i;
    float mean = st1[du] * (1.f / CNT_);
    float var = st1[128 + du] * (1.f / CNT_) - mean * mean;
    float inv = rsqrtf(var + EPS_);
    float pre = fmaxf((g1a[i] - mean) * inv * gamma1[du] + beta1[du], 0.f) + x1a[i] + bias1[du];
    float u = sigm(pre);
    int dc = c0 + i;
    float mean2 = st2[dc] * (1.f / CNT_);
    float var2 = st2[64 + dc] * (1.f / CNT_) - mean2 * mean2;
    float inv2 = rsqrtf(var2 + EPS_);
    float pre2 = fmaxf((g2a[i] - mean2) * inv2 * gamma2[dc] + beta2[dc], 0.f) + x2a[i] + bias2[dc];
    float cc = tanhf(pre2);
    hn[i] = u * ha[i] + (1.f - u) * cc;
  }
  float4 o; o.x = hn[0]; o.y = hn[1]; o.z = hn[2]; o.w = hn[3];
  *(float4*)&h[idx] = o;
  if (writeFeats)
    *(float4*)&out1[(size_t)b * (S_ * N_ * H_) + t * (N_ * H_) + rem] = o;
}

// ---------------------------------------------------------------------------
// Out-layer stage 1: Xot[m][col] ; col<64: hn@W0 (col=b*2+p), col>=64: f1@W1.
// f1 = feats1[t] currently stored in the out feats region.
// ---------------------------------------------------------------------------
__global__ __launch_bounds__(128) void outhk(
    const float* __restrict__ h, const float* __restrict__ out1,
    const float* __restrict__ W0, const float* __restrict__ W1,
    float* __restrict__ Xot, int t, float* __restrict__ zptr, int zn) {
  __shared__ float sh[2048], sf[2048], w0[128], w1[128];
  const int tid = threadIdx.x;
  const int m = blockIdx.x;
  if (m == 0 && tid < zn) zptr[tid] = 0.f;
  for (int i = tid; i < 2048; i += 128) {
    int b = i >> 6, c = i & 63;
    sh[i] = h[(size_t)b * 32768 + m * 64 + c];
    sf[i] = out1[(size_t)b * (S_ * N_ * H_) + t * (N_ * H_) + m * 64 + c];
  }
  w0[tid] = W0[tid];
  w1[tid] = W1[tid];
  __syncthreads();
  const int half = tid >> 6;
  const int b = (tid & 63) >> 1, p = tid & 1;
  const float* src = half ? sf : sh;
  const float* w = half ? w1 : w0;
  float s = 0.f;
#pragma unroll
  for (int c = 0; c < 64; ++c) s = fmaf(src[b * 64 + c], w[c * 2 + p], s);
  Xot[m * 128 + tid] = s;
}

__global__ __launch_bounds__(256) void outfinalk(
    const float* __restrict__ Got, const float* __restrict__ Xot, const float* __restrict__ sto,
    const float* __restrict__ gammao, const float* __restrict__ betao, const float* __restrict__ bo,
    float* __restrict__ out0, int t) {
  const int idx = blockIdx.x * 256 + threadIdx.x;  // 16384 = B*N
  const int b = idx >> 9, n = idx & 511;
  float pr[2];
#pragma unroll
  for (int p = 0; p < 2; ++p) {
    float h0 = Xot[n * 128 + b * 2 + p];
    float go0 = Got[n * 128 + b * 2 + p];
    float h1 = Xot[n * 128 + 64 + b * 2 + p];
    float go1 = Got[n * 128 + 64 + b * 2 + p];
    float mean0 = sto[p] * (1.f / CNT_);
    float var0 = sto[4 + p] * (1.f / CNT_) - mean0 * mean0;
    float inv0 = rsqrtf(var0 + EPS_);
    float mean1 = sto[2 + p] * (1.f / CNT_);
    float var1 = sto[6 + p] * (1.f / CNT_) - mean1 * mean1;
    float inv1 = rsqrtf(var1 + EPS_);
    float o0 = fmaxf((go0 - mean0) * inv0 * gammao[p] + betao[p], 0.f) + h0;
    float o1 = fmaxf((go1 - mean1) * inv1 * gammao[p] + betao[p], 0.f) + h1;
    pr[p] = 0.5f * (o0 + o1) + bo[p];
  }
  float2 v; v.x = pr[0]; v.y = pr[1];
  *(float2*)&out0[(size_t)((b * S_ + t) * N_ + n) * 2] = v;
}

__global__ __launch_bounds__(256) void copyfk(const float* __restrict__ h,
                                              float* __restrict__ out1, int t) {
  const int idx = (blockIdx.x * 256 + threadIdx.x) * 4;
  const int b = idx >> 15, rem = idx & 32767;
  *(float4*)&out1[(size_t)b * (S_ * N_ * H_) + t * (N_ * H_) + rem] =
      *(const float4*)&h[idx];
}

// ---------------------------------------------------------------------------
extern "C" void kernel_launch(void* const* d_in, const int* in_sizes, int n_in,
                              void* d_out, int out_size, void* d_ws, size_t ws_size,
                              hipStream_t stream) {
  (void)in_sizes; (void)n_in; (void)out_size; (void)ws_size;
  const float* inp = (const float*)d_in[0];
  const float* inc = (const float*)d_in[1];
  const float* W1 = (const float*)d_in[2];
  const float* b1 = (const float*)d_in[3];
  const float* g1 = (const float*)d_in[4];
  const float* e1 = (const float*)d_in[5];
  const float* W2 = (const float*)d_in[6];
  const float* b2 = (const float*)d_in[7];
  const float* g2 = (const float*)d_in[8];
  const float* e2 = (const float*)d_in[9];
  const float* W0o = (const float*)d_in[10];
  const float* W1o = (const float*)d_in[11];
  const float* bo = (const float*)d_in[12];
  const float* go = (const float*)d_in[13];
  const float* eo = (const float*)d_in[14];

  // workspace layout (floats); total ~7.8M floats ~31.2 MB
  float* ws = (float*)d_ws;
  float* G = ws;                    // 512*512
  float* Hs = G + 262144;           // 512*128
  float* Hd = Hs + 65536;           // 512*128
  float* h = Hd + 65536;            // B*N*H = 1048576
  float* X1t = h + 1048576;         // 512*4096
  float* G1t = X1t + 2097152;       // 512*4096
  float* X2t = G1t + 2097152;       // 512*2048
  float* G2t = X2t + 1048576;       // 512*2048
  float* Xot = G2t + 1048576;       // 512*128
  float* Got = Xot + 65536;         // 512*128
  float* st1 = Got + 65536;         // 2*128
  float* st2 = st1 + 256;           // 2*64
  float* sto = st2 + 128;           // 2*4

  float* out0 = (float*)d_out;                       // preds (B,S,N,2)
  float* out1 = out0 + (size_t)B_ * S_ * N_ * 2;     // feats  (B,S,N,64)

  // Build G = Hd @ Hs^T once
  k_deg<<<1, 256, 0, stream>>>(inc, Hs, Hd);
  gemmk<64, 64, 4, 4, 0, true><<<dim3(8, 8), 256, 0, stream>>>(
      Hd, Hs, G, 512, 512, 128, 0, nullptr, 0, nullptr, 0);

  for (int dir = 0; dir < 2; ++dir) {
    hipMemsetAsync(h, 0, (size_t)1048576 * sizeof(float), stream);
    for (int ti = 0; ti < S_; ++ti) {
      const int t = dir ? ti : (S_ - 1 - ti);
      // --- cell ---
      xw_cat1<<<256, 256, 0, stream>>>(inp, h, W1, X1t, t, st1, 256);
      gemmk<64, 64, 4, 4, 1, false><<<dim3(64, 8), 256, 0, stream>>>(
          G, X1t, G1t, 512, 4096, 512, 127, st1, 128, nullptr, 0);
      xw_cat2<<<256, 256, 0, stream>>>(inp, h, W2, X2t, G1t, X1t, st1, g1, e1, b1,
                                       t, st2, 128);
      gemmk<64, 64, 4, 4, 1, false><<<dim3(32, 8), 256, 0, stream>>>(
          G, X2t, G2t, 512, 2048, 512, 63, st2, 64, nullptr, 0);
      elt2k<<<1024, 256, 0, stream>>>(G1t, X1t, st1, g1, e1, b1, G2t, X2t, st2,
                                      g2, e2, b2, h, out1, t, dir == 0 ? 1 : 0);
      if (dir == 1) {
        // --- out layer (reads feats1[t] from out1 slot, then overwrites it) ---
        outhk<<<512, 128, 0, stream>>>(h, out1, W0o, W1o, Xot, t, sto, 8);
        gemmk<32, 32, 2, 2, 2, false><<<dim3(4, 16), 256, 0, stream>>>(
            G, Xot, Got, 512, 128, 512, 0, sto, 4, nullptr, 0);
        outfinalk<<<64, 256, 0, stream>>>(Got, Xot, sto, go, eo, bo, out0, t);
        copyfk<<<1024, 256, 0, stream>>>(h, out1, t);
      }
    }
  }
}

// Round 2
// 5757.055 us; speedup vs baseline: 1.5648x; 1.5648x over previous
//
#include <hip/hip_runtime.h>
#include <math.h>

// Problem constants
#define B_   32
#define S_   32
#define N_   512
#define D_   16
#define H_   64
#define D1_  128          // 2*H
#define EPS_ 1e-5f
#define CNT_ 16384.0f     // B*N samples for batchnorm

typedef __attribute__((ext_vector_type(8))) short short8v;
typedef __attribute__((ext_vector_type(4))) float f32x4;

__device__ __forceinline__ float sigm(float x) { return 1.0f / (1.0f + __expf(-x)); }

__device__ __forceinline__ unsigned short f2bf(float x) {
  union { float f; unsigned u; } v; v.f = x;
  unsigned r = (v.u + 0x7fffu + ((v.u >> 16) & 1u)) >> 16;  // RNE
  return (unsigned short)r;
}

// ---------------------------------------------------------------------------
// Degree/scaling factors from incidence matrix H (512x128).
// ---------------------------------------------------------------------------
__global__ __launch_bounds__(256) void k_deg(const float* __restrict__ Hm,
                                             float* __restrict__ Hs,
                                             float* __restrict__ Hd) {
  __shared__ float sdv[512];
  __shared__ float sde[128];
  __shared__ float tmp[256];
  const int tid = threadIdx.x;
  const int e = tid & 127, half = tid >> 7;
  float p = 0.f;
  for (int r = 0; r < 256; ++r) p += Hm[(half * 256 + r) * 128 + e];
  tmp[tid] = p;
  for (int n = tid; n < 512; n += 256) {
    float s = 0.f;
    for (int k = 0; k < 128; k += 4) {
      float4 v = *(const float4*)&Hm[n * 128 + k];
      s += v.x + v.y + v.z + v.w;
    }
    sdv[n] = s;
  }
  __syncthreads();
  if (tid < 128) sde[tid] = tmp[tid] + tmp[tid + 128];
  __syncthreads();
  for (int i = tid; i < 512 * 128; i += 256) {
    int n = i >> 7, ee = i & 127;
    float hv = Hm[i];
    float hs = hv * rsqrtf(sdv[n]);
    Hs[i] = hs;
    Hd[i] = hs / sde[ee];
  }
}

// ---------------------------------------------------------------------------
// fp32 tiled GEMM (kept for G build + tiny out-layer GEMM only).
// ---------------------------------------------------------------------------
template <int BM, int BN, int TM, int TN, int SMODE, bool TRB>
__global__ __launch_bounds__(256) void gemmk(
    const float* __restrict__ A, const float* __restrict__ B, float* __restrict__ C,
    int M, int N, int K, int chmask, float* __restrict__ stats, int statsCH,
    float* __restrict__ zptr, int zn) {
  constexpr int KT = 16;
  __shared__ float As[KT][BM];
  __shared__ float Bs[KT][BN];
  const int tid = threadIdx.x;
  if (zptr && blockIdx.x == 0 && blockIdx.y == 0 && tid < zn) zptr[tid] = 0.f;
  constexpr int NTX = BN / TN;
  const int tx = tid % NTX;
  const int ty = tid / NTX;
  const int n0 = blockIdx.x * BN;
  const int m0 = blockIdx.y * BM;
  float acc[TM][TN];
#pragma unroll
  for (int i = 0; i < TM; ++i)
#pragma unroll
    for (int j = 0; j < TN; ++j) acc[i][j] = 0.f;

  const int ra = tid >> 2;
  const int ca = (tid & 3) * 4;
  constexpr int TPRB = BN / 4;
  const int kb = tid / TPRB;
  const int cb = (tid % TPRB) * 4;

  for (int k0 = 0; k0 < K; k0 += KT) {
    if (ra < BM) {
      float4 v = *(const float4*)&A[(size_t)(m0 + ra) * K + k0 + ca];
      As[ca + 0][ra] = v.x; As[ca + 1][ra] = v.y;
      As[ca + 2][ra] = v.z; As[ca + 3][ra] = v.w;
    }
    if (TRB) {
      if (ra < BN) {
        float4 v = *(const float4*)&B[(size_t)(n0 + ra) * K + k0 + ca];
        Bs[ca + 0][ra] = v.x; Bs[ca + 1][ra] = v.y;
        Bs[ca + 2][ra] = v.z; Bs[ca + 3][ra] = v.w;
      }
    } else {
      if (kb < KT) {
        *(float4*)&Bs[kb][cb] = *(const float4*)&B[(size_t)(k0 + kb) * N + n0 + cb];
      }
    }
    __syncthreads();
#pragma unroll
    for (int kk = 0; kk < KT; ++kk) {
      float a[TM], bv[TN];
#pragma unroll
      for (int i = 0; i < TM; ++i) a[i] = As[kk][ty * TM + i];
#pragma unroll
      for (int j = 0; j < TN; ++j) bv[j] = Bs[kk][tx * TN + j];
#pragma unroll
      for (int i = 0; i < TM; ++i)
#pragma unroll
        for (int j = 0; j < TN; ++j) acc[i][j] = fmaf(a[i], bv[j], acc[i][j]);
    }
    __syncthreads();
  }
#pragma unroll
  for (int i = 0; i < TM; ++i)
#pragma unroll
    for (int j = 0; j < TN; ++j)
      C[(size_t)(m0 + ty * TM + i) * N + n0 + tx * TN + j] = acc[i][j];

  if (SMODE > 0) {
    float* red1 = &As[0][0];
    float* red2 = &Bs[0][0];
    float cs[TN], cq[TN];
#pragma unroll
    for (int j = 0; j < TN; ++j) {
      float s = 0.f, q = 0.f;
#pragma unroll
      for (int i = 0; i < TM; ++i) { s += acc[i][j]; q = fmaf(acc[i][j], acc[i][j], q); }
      cs[j] = s; cq[j] = q;
    }
#pragma unroll
    for (int j = 0; j < TN; ++j) {
      red1[ty * BN + tx * TN + j] = cs[j];
      red2[ty * BN + tx * TN + j] = cq[j];
    }
    __syncthreads();
    if (tid < BN) {
      float s = 0.f, q = 0.f;
      constexpr int NTY = BM / TM;
      for (int r2 = 0; r2 < NTY; ++r2) { s += red1[r2 * BN + tid]; q += red2[r2 * BN + tid]; }
      int gc = n0 + tid;
      int ch = (SMODE == 1) ? (gc & chmask) : (((gc >> 6) & 1) * 2 + (gc & 1));
      atomicAdd(&stats[ch], s);
      atomicAdd(&stats[statsCH + ch], q);
    }
  }
}

// ---------------------------------------------------------------------------
// G (f32, 512x512) -> bf16 copy
// ---------------------------------------------------------------------------
__global__ __launch_bounds__(256) void g2bf(const float* __restrict__ G,
                                            unsigned short* __restrict__ Gb) {
  int i = (blockIdx.x * 256 + threadIdx.x) * 4;
  float4 v = *(const float4*)&G[i];
  ushort4 o;
  o.x = f2bf(v.x); o.y = f2bf(v.y); o.z = f2bf(v.z); o.w = f2bf(v.w);
  *(ushort4*)&Gb[i] = o;
}

// ---------------------------------------------------------------------------
// bf16 MFMA GEMM: C[n][col] = sum_m A[n][m] * B[col][m]  (A=Gb 512x512 row-major,
// B=Xf [col][m] bf16, i.e. X^T). M=512 rows (n), K=512, Nt columns.
// BM=128 (n), BN=64 (col), BK=64. 4 waves: wave (wr,wc) owns 64x32.
// Epilogue: C f32 store + per-channel BN sum/sumsq atomics (ch = col & chmask).
// ---------------------------------------------------------------------------
#define LDST 72   // padded LDS row stride (bf16 elems): 144B, 16B-aligned, conflict-free
__global__ __launch_bounds__(256) void gmfma(
    const short* __restrict__ A, const short* __restrict__ Bf, float* __restrict__ C,
    int Nt, int chmask, float* __restrict__ stats, int statsCH) {
  __shared__ __align__(16) short As[128 * LDST];
  __shared__ __align__(16) short Bs[64 * LDST];
  const int tid = threadIdx.x;
  const int lane = tid & 63;
  const int w = tid >> 6, wr = w >> 1, wc = w & 1;
  const int l15 = lane & 15, l4 = lane >> 4;
  const int col0 = blockIdx.x * 64, n0 = blockIdx.y * 128;
  const int srow = tid >> 3, sch = (tid & 7) * 8;

  f32x4 acc[4][2];
#pragma unroll
  for (int mi = 0; mi < 4; ++mi)
#pragma unroll
    for (int ni = 0; ni < 2; ++ni) acc[mi][ni] = (f32x4)0.f;

  for (int k0 = 0; k0 < 512; k0 += 64) {
#pragma unroll
    for (int q = 0; q < 4; ++q) {
      int row = srow + q * 32;
      *(short8v*)&As[row * LDST + sch] =
          *(const short8v*)&A[(size_t)(n0 + row) * 512 + k0 + sch];
    }
#pragma unroll
    for (int q = 0; q < 2; ++q) {
      int row = srow + q * 32;
      *(short8v*)&Bs[row * LDST + sch] =
          *(const short8v*)&Bf[(size_t)(col0 + row) * 512 + k0 + sch];
    }
    __syncthreads();
#pragma unroll
    for (int kk = 0; kk < 64; kk += 32) {
      short8v av[4], bv[2];
#pragma unroll
      for (int mi = 0; mi < 4; ++mi)
        av[mi] = *(const short8v*)&As[(wr * 64 + mi * 16 + l15) * LDST + kk + l4 * 8];
#pragma unroll
      for (int ni = 0; ni < 2; ++ni)
        bv[ni] = *(const short8v*)&Bs[(wc * 32 + ni * 16 + l15) * LDST + kk + l4 * 8];
#pragma unroll
      for (int mi = 0; mi < 4; ++mi)
#pragma unroll
        for (int ni = 0; ni < 2; ++ni)
          acc[mi][ni] = __builtin_amdgcn_mfma_f32_16x16x32_bf16(av[mi], bv[ni],
                                                                acc[mi][ni], 0, 0, 0);
    }
    __syncthreads();
  }

  float cs[2] = {0.f, 0.f}, cq[2] = {0.f, 0.f};
#pragma unroll
  for (int mi = 0; mi < 4; ++mi)
#pragma unroll
    for (int ni = 0; ni < 2; ++ni)
#pragma unroll
      for (int r = 0; r < 4; ++r) {
        float val = acc[mi][ni][r];
        C[(size_t)(n0 + wr * 64 + mi * 16 + l4 * 4 + r) * Nt + col0 + wc * 32 + ni * 16 + l15] = val;
        cs[ni] += val;
        cq[ni] = fmaf(val, val, cq[ni]);
      }
  // BN-stat reduce: 64 in-block cols x 8 owners (wr x l4)
  float* red = (float*)As;
  const int owner = wr * 4 + l4;
#pragma unroll
  for (int ni = 0; ni < 2; ++ni) {
    int cb = wc * 32 + ni * 16 + l15;
    red[cb * 8 + owner] = cs[ni];
    red[512 + cb * 8 + owner] = cq[ni];
  }
  __syncthreads();
  if (tid < 64) {
    float s = 0.f, q = 0.f;
    for (int o = 0; o < 8; ++o) { s += red[tid * 8 + o]; q += red[512 + tid * 8 + o]; }
    int ch = (col0 + tid) & chmask;
    atomicAdd(&stats[ch], s);
    atomicAdd(&stats[statsCH + ch], q);
  }
}

// ---------------------------------------------------------------------------
// X1t[m][b*128+d] = cat(x_t, h)[b,m,:80] @ W1  (f32) + bf16 transposed copy
// Xf1[(b*128+d)*512 + m]. Grid: 256 blocks = (b<<3 | mblk), 64 m-rows each.
// ---------------------------------------------------------------------------
__global__ __launch_bounds__(256) void xw_cat1(
    const float* __restrict__ inp, const float* __restrict__ h,
    const float* __restrict__ W, float* __restrict__ X1t,
    unsigned short* __restrict__ Xf1, int t,
    float* __restrict__ zptr, int zn) {
  __shared__ float As[80][64];
  __shared__ float Ws[80][128];
  const int tid = threadIdx.x;
  const int bid = blockIdx.x;
  const int b = bid >> 3, m0 = (bid & 7) * 64;
  if (bid == 0 && tid < zn) zptr[tid] = 0.f;
  for (int i = tid * 4; i < 80 * 128; i += 1024)
    *(float4*)(((float*)Ws) + i) = *(const float4*)&W[i];
  const int rl = tid >> 2;
  const int m = m0 + rl;
  const int k4 = (tid & 3) * 4;
  {
    float4 v = *(const float4*)&inp[(size_t)((b * S_ + t) * N_ + m) * D_ + k4];
    As[k4 + 0][rl] = v.x; As[k4 + 1][rl] = v.y; As[k4 + 2][rl] = v.z; As[k4 + 3][rl] = v.w;
  }
#pragma unroll
  for (int q = 0; q < 4; ++q) {
    int c = (tid & 3) * 16 + q * 4;
    float4 v = *(const float4*)&h[(size_t)(b * N_ + m) * H_ + c];
    As[16 + c + 0][rl] = v.x; As[16 + c + 1][rl] = v.y;
    As[16 + c + 2][rl] = v.z; As[16 + c + 3][rl] = v.w;
  }
  __syncthreads();
  const int tx = tid & 15, ty = tid >> 4;
  float acc[4][8];
#pragma unroll
  for (int i = 0; i < 4; ++i)
#pragma unroll
    for (int j = 0; j < 8; ++j) acc[i][j] = 0.f;
  for (int k = 0; k < 80; ++k) {
    float a[4], bv[8];
#pragma unroll
    for (int i = 0; i < 4; ++i) a[i] = As[k][ty * 4 + i];
#pragma unroll
    for (int j = 0; j < 8; ++j) bv[j] = Ws[k][tx * 8 + j];
#pragma unroll
    for (int i = 0; i < 4; ++i)
#pragma unroll
      for (int j = 0; j < 8; ++j) acc[i][j] = fmaf(a[i], bv[j], acc[i][j]);
  }
#pragma unroll
  for (int i = 0; i < 4; ++i) {
    const int mi = m0 + ty * 4 + i;
    float4 v0; v0.x = acc[i][0]; v0.y = acc[i][1]; v0.z = acc[i][2]; v0.w = acc[i][3];
    float4 v1; v1.x = acc[i][4]; v1.y = acc[i][5]; v1.z = acc[i][6]; v1.w = acc[i][7];
    *(float4*)&X1t[(size_t)mi * 4096 + b * 128 + tx * 8] = v0;
    *(float4*)&X1t[(size_t)mi * 4096 + b * 128 + tx * 8 + 4] = v1;
  }
#pragma unroll
  for (int j = 0; j < 8; ++j) {
    int g = b * 128 + tx * 8 + j;
    ushort4 o;
    o.x = f2bf(acc[0][j]); o.y = f2bf(acc[1][j]);
    o.z = f2bf(acc[2][j]); o.w = f2bf(acc[3][j]);
    *(ushort4*)&Xf1[(size_t)g * 512 + m0 + ty * 4] = o;
  }
}

// ---------------------------------------------------------------------------
// X2t = cat(x_t, r*h) @ W2 with fused r-gate; dual write (f32 + bf16 X^T).
// ---------------------------------------------------------------------------
__global__ __launch_bounds__(256) void xw_cat2(
    const float* __restrict__ inp, const float* __restrict__ h,
    const float* __restrict__ W, float* __restrict__ X2t,
    unsigned short* __restrict__ Xf2,
    const float* __restrict__ G1t, const float* __restrict__ X1t,
    const float* __restrict__ st1, const float* __restrict__ gamma1,
    const float* __restrict__ beta1, const float* __restrict__ bias1,
    int t, float* __restrict__ zptr, int zn) {
  __shared__ float As[80][64];
  __shared__ float Ws[80][64];
  __shared__ float sm[128], sa[128], sb[128], sbb[128];
  const int tid = threadIdx.x;
  const int bid = blockIdx.x;
  const int b = bid >> 3, m0 = (bid & 7) * 64;
  if (bid == 0 && tid < zn) zptr[tid] = 0.f;
  if (tid < 128) {
    float mean = st1[tid] * (1.f / CNT_);
    float var = fmaf(st1[128 + tid], 1.f / CNT_, -mean * mean);
    float inv = rsqrtf(var + EPS_);
    sm[tid] = mean; sa[tid] = inv * gamma1[tid];
    sb[tid] = beta1[tid]; sbb[tid] = bias1[tid];
  }
  __syncthreads();
  for (int i = tid * 4; i < 80 * 64; i += 1024)
    *(float4*)(((float*)Ws) + i) = *(const float4*)&W[i];
  const int rl = tid >> 2;
  const int m = m0 + rl;
  const int k4 = (tid & 3) * 4;
  {
    float4 v = *(const float4*)&inp[(size_t)((b * S_ + t) * N_ + m) * D_ + k4];
    As[k4 + 0][rl] = v.x; As[k4 + 1][rl] = v.y; As[k4 + 2][rl] = v.z; As[k4 + 3][rl] = v.w;
  }
#pragma unroll
  for (int q = 0; q < 4; ++q) {
    int c = (tid & 3) * 16 + q * 4;
    float4 hv = *(const float4*)&h[(size_t)(b * N_ + m) * H_ + c];
    int j0 = m * H_ + c;
    int n = j0 >> 7;
    int dd = j0 & 127;
    float4 gv = *(const float4*)&G1t[(size_t)n * 4096 + b * 128 + dd];
    float4 xv = *(const float4*)&X1t[(size_t)n * 4096 + b * 128 + dd];
    float hva[4] = {hv.x, hv.y, hv.z, hv.w};
    float gva[4] = {gv.x, gv.y, gv.z, gv.w};
    float xva[4] = {xv.x, xv.y, xv.z, xv.w};
#pragma unroll
    for (int i2 = 0; i2 < 4; ++i2) {
      int d2 = dd + i2;
      float pre = fmaf(gva[i2] - sm[d2], sa[d2], sb[d2]);
      pre = fmaxf(pre, 0.f) + xva[i2] + sbb[d2];
      As[16 + c + i2][rl] = sigm(pre) * hva[i2];
    }
  }
  __syncthreads();
  const int tx = tid & 15, ty = tid >> 4;
  float acc[4][4];
#pragma unroll
  for (int i = 0; i < 4; ++i)
#pragma unroll
    for (int j = 0; j < 4; ++j) acc[i][j] = 0.f;
  for (int k = 0; k < 80; ++k) {
    float a[4], bv[4];
#pragma unroll
    for (int i = 0; i < 4; ++i) a[i] = As[k][ty * 4 + i];
#pragma unroll
    for (int j = 0; j < 4; ++j) bv[j] = Ws[k][tx * 4 + j];
#pragma unroll
    for (int i = 0; i < 4; ++i)
#pragma unroll
      for (int j = 0; j < 4; ++j) acc[i][j] = fmaf(a[i], bv[j], acc[i][j]);
  }
#pragma unroll
  for (int i = 0; i < 4; ++i) {
    const int mi = m0 + ty * 4 + i;
    float4 v0; v0.x = acc[i][0]; v0.y = acc[i][1]; v0.z = acc[i][2]; v0.w = acc[i][3];
    *(float4*)&X2t[(size_t)mi * 2048 + b * 64 + tx * 4] = v0;
  }
#pragma unroll
  for (int j = 0; j < 4; ++j) {
    int g = b * 64 + tx * 4 + j;
    ushort4 o;
    o.x = f2bf(acc[0][j]); o.y = f2bf(acc[1][j]);
    o.z = f2bf(acc[2][j]); o.w = f2bf(acc[3][j]);
    *(ushort4*)&Xf2[(size_t)g * 512 + m0 + ty * 4] = o;
  }
}

// ---------------------------------------------------------------------------
// u-gate + c=tanh(.) + h update; optional feats1 write.
// ---------------------------------------------------------------------------
__global__ __launch_bounds__(256) void elt2k(
    const float* __restrict__ G1t, const float* __restrict__ X1t, const float* __restrict__ st1,
    const float* __restrict__ gamma1, const float* __restrict__ beta1, const float* __restrict__ bias1,
    const float* __restrict__ G2t, const float* __restrict__ X2t, const float* __restrict__ st2,
    const float* __restrict__ gamma2, const float* __restrict__ beta2, const float* __restrict__ bias2,
    float* __restrict__ h, float* __restrict__ out1, int t, int writeFeats) {
  const int idx = (blockIdx.x * 256 + threadIdx.x) * 4;
  const int b = idx >> 15;
  const int rem = idx & 32767;
  const int m = rem >> 6, c0 = rem & 63;
  const int nu = 256 + (rem >> 7);
  const int ddu = rem & 127;
  float4 g1v = *(const float4*)&G1t[(size_t)nu * 4096 + b * 128 + ddu];
  float4 x1v = *(const float4*)&X1t[(size_t)nu * 4096 + b * 128 + ddu];
  float4 g2v = *(const float4*)&G2t[(size_t)m * 2048 + b * 64 + c0];
  float4 x2v = *(const float4*)&X2t[(size_t)m * 2048 + b * 64 + c0];
  float4 hv = *(const float4*)&h[idx];
  float g1a[4] = {g1v.x, g1v.y, g1v.z, g1v.w};
  float x1a[4] = {x1v.x, x1v.y, x1v.z, x1v.w};
  float g2a[4] = {g2v.x, g2v.y, g2v.z, g2v.w};
  float x2a[4] = {x2v.x, x2v.y, x2v.z, x2v.w};
  float ha[4] = {hv.x, hv.y, hv.z, hv.w};
  float hn[4];
#pragma unroll
  for (int i = 0; i < 4; ++i) {
    int du = ddu + i;
    float mean = st1[du] * (1.f / CNT_);
    float var = st1[128 + du] * (1.f / CNT_) - mean * mean;
    float inv = rsqrtf(var + EPS_);
    float pre = fmaxf((g1a[i] - mean) * inv * gamma1[du] + beta1[du], 0.f) + x1a[i] + bias1[du];
    float u = sigm(pre);
    int dc = c0 + i;
    float mean2 = st2[dc] * (1.f / CNT_);
    float var2 = st2[64 + dc] * (1.f / CNT_) - mean2 * mean2;
    float inv2 = rsqrtf(var2 + EPS_);
    float pre2 = fmaxf((g2a[i] - mean2) * inv2 * gamma2[dc] + beta2[dc], 0.f) + x2a[i] + bias2[dc];
    float cc = tanhf(pre2);
    hn[i] = u * ha[i] + (1.f - u) * cc;
  }
  float4 o; o.x = hn[0]; o.y = hn[1]; o.z = hn[2]; o.w = hn[3];
  *(float4*)&h[idx] = o;
  if (writeFeats)
    *(float4*)&out1[(size_t)b * (S_ * N_ * H_) + t * (N_ * H_) + rem] = o;
}

// ---------------------------------------------------------------------------
// Out-layer stage 1
// ---------------------------------------------------------------------------
__global__ __launch_bounds__(128) void outhk(
    const float* __restrict__ h, const float* __restrict__ out1,
    const float* __restrict__ W0, const float* __restrict__ W1,
    float* __restrict__ Xot, int t, float* __restrict__ zptr, int zn) {
  __shared__ float sh[2048], sf[2048], w0[128], w1[128];
  const int tid = threadIdx.x;
  const int m = blockIdx.x;
  if (m == 0 && tid < zn) zptr[tid] = 0.f;
  for (int i = tid; i < 2048; i += 128) {
    int b = i >> 6, c = i & 63;
    sh[i] = h[(size_t)b * 32768 + m * 64 + c];
    sf[i] = out1[(size_t)b * (S_ * N_ * H_) + t * (N_ * H_) + m * 64 + c];
  }
  w0[tid] = W0[tid];
  w1[tid] = W1[tid];
  __syncthreads();
  const int half = tid >> 6;
  const int b = (tid & 63) >> 1, p = tid & 1;
  const float* src = half ? sf : sh;
  const float* w = half ? w1 : w0;
  float s = 0.f;
#pragma unroll
  for (int c = 0; c < 64; ++c) s = fmaf(src[b * 64 + c], w[c * 2 + p], s);
  Xot[m * 128 + tid] = s;
}

__global__ __launch_bounds__(256) void outfinalk(
    const float* __restrict__ Got, const float* __restrict__ Xot, const float* __restrict__ sto,
    const float* __restrict__ gammao, const float* __restrict__ betao, const float* __restrict__ bo,
    float* __restrict__ out0, int t) {
  const int idx = blockIdx.x * 256 + threadIdx.x;
  const int b = idx >> 9, n = idx & 511;
  float pr[2];
#pragma unroll
  for (int p = 0; p < 2; ++p) {
    float h0 = Xot[n * 128 + b * 2 + p];
    float go0 = Got[n * 128 + b * 2 + p];
    float h1 = Xot[n * 128 + 64 + b * 2 + p];
    float go1 = Got[n * 128 + 64 + b * 2 + p];
    float mean0 = sto[p] * (1.f / CNT_);
    float var0 = sto[4 + p] * (1.f / CNT_) - mean0 * mean0;
    float inv0 = rsqrtf(var0 + EPS_);
    float mean1 = sto[2 + p] * (1.f / CNT_);
    float var1 = sto[6 + p] * (1.f / CNT_) - mean1 * mean1;
    float inv1 = rsqrtf(var1 + EPS_);
    float o0 = fmaxf((go0 - mean0) * inv0 * gammao[p] + betao[p], 0.f) + h0;
    float o1 = fmaxf((go1 - mean1) * inv1 * gammao[p] + betao[p], 0.f) + h1;
    pr[p] = 0.5f * (o0 + o1) + bo[p];
  }
  float2 v; v.x = pr[0]; v.y = pr[1];
  *(float2*)&out0[(size_t)((b * S_ + t) * N_ + n) * 2] = v;
}

__global__ __launch_bounds__(256) void copyfk(const float* __restrict__ h,
                                              float* __restrict__ out1, int t) {
  const int idx = (blockIdx.x * 256 + threadIdx.x) * 4;
  const int b = idx >> 15, rem = idx & 32767;
  *(float4*)&out1[(size_t)b * (S_ * N_ * H_) + t * (N_ * H_) + rem] =
      *(const float4*)&h[idx];
}

// ---------------------------------------------------------------------------
extern "C" void kernel_launch(void* const* d_in, const int* in_sizes, int n_in,
                              void* d_out, int out_size, void* d_ws, size_t ws_size,
                              hipStream_t stream) {
  (void)in_sizes; (void)n_in; (void)out_size; (void)ws_size;
  const float* inp = (const float*)d_in[0];
  const float* inc = (const float*)d_in[1];
  const float* W1 = (const float*)d_in[2];
  const float* b1 = (const float*)d_in[3];
  const float* g1 = (const float*)d_in[4];
  const float* e1 = (const float*)d_in[5];
  const float* W2 = (const float*)d_in[6];
  const float* b2 = (const float*)d_in[7];
  const float* g2 = (const float*)d_in[8];
  const float* e2 = (const float*)d_in[9];
  const float* W0o = (const float*)d_in[10];
  const float* W1o = (const float*)d_in[11];
  const float* bo = (const float*)d_in[12];
  const float* go = (const float*)d_in[13];
  const float* eo = (const float*)d_in[14];

  // workspace layout (float slots); ~9.6M floats ~38 MB
  float* ws = (float*)d_ws;
  float* G   = ws;                  // 512*512
  float* Hs  = G + 262144;          // 512*128
  float* Hd  = Hs + 65536;          // 512*128
  float* h   = Hd + 65536;          // 1048576
  float* X1t = h + 1048576;         // 512*4096
  float* G1t = X1t + 2097152;       // 512*4096
  float* X2t = G1t + 2097152;       // 512*2048
  float* G2t = X2t + 1048576;       // 512*2048
  float* Xot = G2t + 1048576;       // 512*128
  float* Got = Xot + 65536;         // 512*128
  float* st1 = Got + 65536;         // 256
  float* st2 = st1 + 256;           // 128
  float* sto = st2 + 128;           // 8 (pad to 640 total)
  float* after = st1 + 1024;
  unsigned short* Gb  = (unsigned short*)after;            // 512*512 bf16
  unsigned short* Xf1 = (unsigned short*)(after + 131072); // 4096*512 bf16
  unsigned short* Xf2 = (unsigned short*)(after + 131072 + 1048576); // 2048*512

  float* out0 = (float*)d_out;
  float* out1 = out0 + (size_t)B_ * S_ * N_ * 2;

  // Build G = Hd @ Hs^T once; bf16 copy
  k_deg<<<1, 256, 0, stream>>>(inc, Hs, Hd);
  gemmk<64, 64, 4, 4, 0, true><<<dim3(8, 8), 256, 0, stream>>>(
      Hd, Hs, G, 512, 512, 128, 0, nullptr, 0, nullptr, 0);
  g2bf<<<256, 256, 0, stream>>>(G, Gb);

  for (int dir = 0; dir < 2; ++dir) {
    hipMemsetAsync(h, 0, (size_t)1048576 * sizeof(float), stream);
    for (int ti = 0; ti < S_; ++ti) {
      const int t = dir ? ti : (S_ - 1 - ti);
      xw_cat1<<<256, 256, 0, stream>>>(inp, h, W1, X1t, Xf1, t, st1, 256);
      gmfma<<<dim3(64, 4), 256, 0, stream>>>((const short*)Gb, (const short*)Xf1,
                                             G1t, 4096, 127, st1, 128);
      xw_cat2<<<256, 256, 0, stream>>>(inp, h, W2, X2t, Xf2, G1t, X1t, st1, g1,
                                       e1, b1, t, st2, 128);
      gmfma<<<dim3(32, 4), 256, 0, stream>>>((const short*)Gb, (const short*)Xf2,
                                             G2t, 2048, 63, st2, 64);
      elt2k<<<1024, 256, 0, stream>>>(G1t, X1t, st1, g1, e1, b1, G2t, X2t, st2,
                                      g2, e2, b2, h, out1, t, dir == 0 ? 1 : 0);
      if (dir == 1) {
        outhk<<<512, 128, 0, stream>>>(h, out1, W0o, W1o, Xot, t, sto, 8);
        gemmk<32, 32, 2, 2, 2, false><<<dim3(4, 16), 256, 0, stream>>>(
            G, Xot, Got, 512, 128, 512, 0, sto, 4, nullptr, 0);
        outfinalk<<<64, 256, 0, stream>>>(Got, Xot, sto, go, eo, bo, out0, t);
        copyfk<<<1024, 256, 0, stream>>>(h, out1, t);
      }
    }
  }
}

// Round 5
// 5429.501 us; speedup vs baseline: 1.6591x; 1.0603x over previous
//
#include <hip/hip_runtime.h>
#include <math.h>

// Problem constants
#define B_   32
#define S_   32
#define N_   512
#define D_   16
#define H_   64
#define D1_  128          // 2*H
#define EPS_ 1e-5f
#define CNT_ 16384.0f     // B*N samples for batchnorm
#define SNH_ 1048576      // S*N*H (per-batch feats stride)
#define NH_  32768        // N*H  (per-timestep feats stride)

typedef __attribute__((ext_vector_type(8))) short short8v;
typedef __attribute__((ext_vector_type(8))) _Float16 f16x8;
typedef __attribute__((ext_vector_type(4))) float f32x4;

__device__ __forceinline__ float sigm(float x) { return 1.0f / (1.0f + __expf(-x)); }

__device__ __forceinline__ unsigned short f2h(float x) {
  union { _Float16 h; unsigned short u; } c;
  c.h = (_Float16)x;
  return c.u;
}

// ---------------------------------------------------------------------------
// Degree/scaling factors from incidence matrix H (512x128).
// ---------------------------------------------------------------------------
__global__ __launch_bounds__(256) void k_deg(const float* __restrict__ Hm,
                                             float* __restrict__ Hs,
                                             float* __restrict__ Hd) {
  __shared__ float sdv[512];
  __shared__ float sde[128];
  __shared__ float tmp[256];
  const int tid = threadIdx.x;
  const int e = tid & 127, half = tid >> 7;
  float p = 0.f;
  for (int r = 0; r < 256; ++r) p += Hm[(half * 256 + r) * 128 + e];
  tmp[tid] = p;
  for (int n = tid; n < 512; n += 256) {
    float s = 0.f;
    for (int k = 0; k < 128; k += 4) {
      float4 v = *(const float4*)&Hm[n * 128 + k];
      s += v.x + v.y + v.z + v.w;
    }
    sdv[n] = s;
  }
  __syncthreads();
  if (tid < 128) sde[tid] = tmp[tid] + tmp[tid + 128];
  __syncthreads();
  for (int i = tid; i < 512 * 128; i += 256) {
    int n = i >> 7, ee = i & 127;
    float hv = Hm[i];
    float hs = hv * rsqrtf(sdv[n]);
    Hs[i] = hs;
    Hd[i] = hs / sde[ee];
  }
}

// ---------------------------------------------------------------------------
// fp32 tiled GEMM (G build + tiny out-layer GEMM only).
// ---------------------------------------------------------------------------
template <int BM, int BN, int TM, int TN, int SMODE, bool TRB>
__global__ __launch_bounds__(256) void gemmk(
    const float* __restrict__ A, const float* __restrict__ B, float* __restrict__ C,
    int M, int N, int K, int chmask, float* __restrict__ stats, int statsCH,
    float* __restrict__ zptr, int zn) {
  constexpr int KT = 16;
  __shared__ float As[KT][BM];
  __shared__ float Bs[KT][BN];
  const int tid = threadIdx.x;
  if (zptr && blockIdx.x == 0 && blockIdx.y == 0 && tid < zn) zptr[tid] = 0.f;
  constexpr int NTX = BN / TN;
  const int tx = tid % NTX;
  const int ty = tid / NTX;
  const int n0 = blockIdx.x * BN;
  const int m0 = blockIdx.y * BM;
  float acc[TM][TN];
#pragma unroll
  for (int i = 0; i < TM; ++i)
#pragma unroll
    for (int j = 0; j < TN; ++j) acc[i][j] = 0.f;

  const int ra = tid >> 2;
  const int ca = (tid & 3) * 4;
  constexpr int TPRB = BN / 4;
  const int kb = tid / TPRB;
  const int cb = (tid % TPRB) * 4;

  for (int k0 = 0; k0 < K; k0 += KT) {
    if (ra < BM) {
      float4 v = *(const float4*)&A[(size_t)(m0 + ra) * K + k0 + ca];
      As[ca + 0][ra] = v.x; As[ca + 1][ra] = v.y;
      As[ca + 2][ra] = v.z; As[ca + 3][ra] = v.w;
    }
    if (TRB) {
      if (ra < BN) {
        float4 v = *(const float4*)&B[(size_t)(n0 + ra) * K + k0 + ca];
        Bs[ca + 0][ra] = v.x; Bs[ca + 1][ra] = v.y;
        Bs[ca + 2][ra] = v.z; Bs[ca + 3][ra] = v.w;
      }
    } else {
      if (kb < KT) {
        *(float4*)&Bs[kb][cb] = *(const float4*)&B[(size_t)(k0 + kb) * N + n0 + cb];
      }
    }
    __syncthreads();
#pragma unroll
    for (int kk = 0; kk < KT; ++kk) {
      float a[TM], bv[TN];
#pragma unroll
      for (int i = 0; i < TM; ++i) a[i] = As[kk][ty * TM + i];
#pragma unroll
      for (int j = 0; j < TN; ++j) bv[j] = Bs[kk][tx * TN + j];
#pragma unroll
      for (int i = 0; i < TM; ++i)
#pragma unroll
        for (int j = 0; j < TN; ++j) acc[i][j] = fmaf(a[i], bv[j], acc[i][j]);
    }
    __syncthreads();
  }
#pragma unroll
  for (int i = 0; i < TM; ++i)
#pragma unroll
    for (int j = 0; j < TN; ++j)
      C[(size_t)(m0 + ty * TM + i) * N + n0 + tx * TN + j] = acc[i][j];

  if (SMODE > 0) {
    float* red1 = &As[0][0];
    float* red2 = &Bs[0][0];
    float cs[TN], cq[TN];
#pragma unroll
    for (int j = 0; j < TN; ++j) {
      float s = 0.f, q = 0.f;
#pragma unroll
      for (int i = 0; i < TM; ++i) { s += acc[i][j]; q = fmaf(acc[i][j], acc[i][j], q); }
      cs[j] = s; cq[j] = q;
    }
#pragma unroll
    for (int j = 0; j < TN; ++j) {
      red1[ty * BN + tx * TN + j] = cs[j];
      red2[ty * BN + tx * TN + j] = cq[j];
    }
    __syncthreads();
    if (tid < BN) {
      float s = 0.f, q = 0.f;
      constexpr int NTY = BM / TM;
      for (int r2 = 0; r2 < NTY; ++r2) { s += red1[r2 * BN + tid]; q += red2[r2 * BN + tid]; }
      int gc = n0 + tid;
      int ch = (SMODE == 1) ? (gc & chmask) : (((gc >> 6) & 1) * 2 + (gc & 1));
      atomicAdd(&stats[ch], s);
      atomicAdd(&stats[statsCH + ch], q);
    }
  }
}

// ---------------------------------------------------------------------------
// G (f32, 512x512) -> fp16 copy
// ---------------------------------------------------------------------------
__global__ __launch_bounds__(256) void g2h(const float* __restrict__ G,
                                           unsigned short* __restrict__ Gh) {
  int i = (blockIdx.x * 256 + threadIdx.x) * 4;
  float4 v = *(const float4*)&G[i];
  ushort4 o;
  o.x = f2h(v.x); o.y = f2h(v.y); o.z = f2h(v.z); o.w = f2h(v.w);
  *(ushort4*)&Gh[i] = o;
}

// ---------------------------------------------------------------------------
// fp16 MFMA GEMM: C[n][col] = sum_m A[n][m] * B[col][m].
// A = Gh (512x512 row-major), B = Xf (X^T, [col][m]). BM=128, BN=64, BK=64.
// Register-prefetch double buffering. Epilogue: C f32 + BN sum/sumsq atomics.
// ---------------------------------------------------------------------------
#define LDST 72
__global__ __launch_bounds__(256) void gmfma(
    const unsigned short* __restrict__ A, const unsigned short* __restrict__ Bf,
    float* __restrict__ C, int Nt, int chmask, float* __restrict__ stats,
    int statsCH) {
  __shared__ __align__(16) unsigned short As[128 * LDST];
  __shared__ __align__(16) unsigned short Bs[64 * LDST];
  const int tid = threadIdx.x;
  const int lane = tid & 63;
  const int w = tid >> 6, wr = w >> 1, wc = w & 1;
  const int l15 = lane & 15, l4 = lane >> 4;
  const int col0 = blockIdx.x * 64, n0 = blockIdx.y * 128;
  const int srow = tid >> 3, sch = (tid & 7) * 8;

  f32x4 acc[4][2];
#pragma unroll
  for (int mi = 0; mi < 4; ++mi)
#pragma unroll
    for (int ni = 0; ni < 2; ++ni) acc[mi][ni] = (f32x4)0.f;

  short8v pa[4], pb[2];
#pragma unroll
  for (int q = 0; q < 4; ++q)
    pa[q] = *(const short8v*)&A[(size_t)(n0 + srow + q * 32) * 512 + sch];
#pragma unroll
  for (int q = 0; q < 2; ++q)
    pb[q] = *(const short8v*)&Bf[(size_t)(col0 + srow + q * 32) * 512 + sch];

  for (int k0 = 0; k0 < 512; k0 += 64) {
#pragma unroll
    for (int q = 0; q < 4; ++q)
      *(short8v*)&As[(srow + q * 32) * LDST + sch] = pa[q];
#pragma unroll
    for (int q = 0; q < 2; ++q)
      *(short8v*)&Bs[(srow + q * 32) * LDST + sch] = pb[q];
    __syncthreads();
    if (k0 < 448) {
      int kn = k0 + 64;
#pragma unroll
      for (int q = 0; q < 4; ++q)
        pa[q] = *(const short8v*)&A[(size_t)(n0 + srow + q * 32) * 512 + kn + sch];
#pragma unroll
      for (int q = 0; q < 2; ++q)
        pb[q] = *(const short8v*)&Bf[(size_t)(col0 + srow + q * 32) * 512 + kn + sch];
    }
#pragma unroll
    for (int kk = 0; kk < 64; kk += 32) {
      f16x8 av[4], bv[2];
#pragma unroll
      for (int mi = 0; mi < 4; ++mi)
        av[mi] = *(const f16x8*)&As[(wr * 64 + mi * 16 + l15) * LDST + kk + l4 * 8];
#pragma unroll
      for (int ni = 0; ni < 2; ++ni)
        bv[ni] = *(const f16x8*)&Bs[(wc * 32 + ni * 16 + l15) * LDST + kk + l4 * 8];
#pragma unroll
      for (int mi = 0; mi < 4; ++mi)
#pragma unroll
        for (int ni = 0; ni < 2; ++ni)
          acc[mi][ni] = __builtin_amdgcn_mfma_f32_16x16x32_f16(av[mi], bv[ni],
                                                               acc[mi][ni], 0, 0, 0);
    }
    __syncthreads();
  }

  float cs[2] = {0.f, 0.f}, cq[2] = {0.f, 0.f};
#pragma unroll
  for (int mi = 0; mi < 4; ++mi)
#pragma unroll
    for (int ni = 0; ni < 2; ++ni)
#pragma unroll
      for (int r = 0; r < 4; ++r) {
        float val = acc[mi][ni][r];
        C[(size_t)(n0 + wr * 64 + mi * 16 + l4 * 4 + r) * Nt + col0 + wc * 32 + ni * 16 + l15] = val;
        cs[ni] += val;
        cq[ni] = fmaf(val, val, cq[ni]);
      }
  float* red = (float*)As;
  const int owner = wr * 4 + l4;
#pragma unroll
  for (int ni = 0; ni < 2; ++ni) {
    int cb = wc * 32 + ni * 16 + l15;
    red[cb * 8 + owner] = cs[ni];
    red[512 + cb * 8 + owner] = cq[ni];
  }
  __syncthreads();
  if (tid < 64) {
    float s = 0.f, q = 0.f;
    for (int o = 0; o < 8; ++o) { s += red[tid * 8 + o]; q += red[512 + tid * 8 + o]; }
    int ch = (col0 + tid) & chmask;
    atomicAdd(&stats[ch], s);
    atomicAdd(&stats[statsCH + ch], q);
  }
}

// ---------------------------------------------------------------------------
// Standalone X1 projection (first step of each direction; h from memory).
// Writes split X1 f32 (lo rows 0..255 / hi rows 256..511) + fp16 X^T.
// ---------------------------------------------------------------------------
__global__ __launch_bounds__(256) void xw_cat1(
    const float* __restrict__ inp, const float* __restrict__ h,
    const float* __restrict__ W, float* __restrict__ X1lo,
    float* __restrict__ X1hi, unsigned short* __restrict__ Xf1, int t,
    float* __restrict__ zptr, int zn) {
  __shared__ float As[80][64];
  __shared__ float Ws[80][128];
  const int tid = threadIdx.x;
  const int bid = blockIdx.x;
  const int b = bid >> 3, m0 = (bid & 7) * 64;
  if (bid == 0 && tid < zn) zptr[tid] = 0.f;
  for (int i = tid * 4; i < 80 * 128; i += 1024)
    *(float4*)(((float*)Ws) + i) = *(const float4*)&W[i];
  const int rl = tid >> 2;
  const int m = m0 + rl;
  const int k4 = (tid & 3) * 4;
  {
    float4 v = *(const float4*)&inp[(size_t)((b * S_ + t) * N_ + m) * D_ + k4];
    As[k4 + 0][rl] = v.x; As[k4 + 1][rl] = v.y; As[k4 + 2][rl] = v.z; As[k4 + 3][rl] = v.w;
  }
#pragma unroll
  for (int q = 0; q < 4; ++q) {
    int c = (tid & 3) * 16 + q * 4;
    float4 v = *(const float4*)&h[(size_t)(b * N_ + m) * H_ + c];
    As[16 + c + 0][rl] = v.x; As[16 + c + 1][rl] = v.y;
    As[16 + c + 2][rl] = v.z; As[16 + c + 3][rl] = v.w;
  }
  __syncthreads();
  const int tx = tid & 15, ty = tid >> 4;
  float acc[4][8];
#pragma unroll
  for (int i = 0; i < 4; ++i)
#pragma unroll
    for (int j = 0; j < 8; ++j) acc[i][j] = 0.f;
  for (int k = 0; k < 80; ++k) {
    float a[4], bv[8];
#pragma unroll
    for (int i = 0; i < 4; ++i) a[i] = As[k][ty * 4 + i];
#pragma unroll
    for (int j = 0; j < 8; ++j) bv[j] = Ws[k][tx * 8 + j];
#pragma unroll
    for (int i = 0; i < 4; ++i)
#pragma unroll
      for (int j = 0; j < 8; ++j) acc[i][j] = fmaf(a[i], bv[j], acc[i][j]);
  }
  float* Xd = (m0 < 256) ? X1lo : X1hi;
  const int mb = (m0 < 256) ? m0 : (m0 - 256);
#pragma unroll
  for (int i = 0; i < 4; ++i) {
    const int mi = mb + ty * 4 + i;
    float4 v0; v0.x = acc[i][0]; v0.y = acc[i][1]; v0.z = acc[i][2]; v0.w = acc[i][3];
    float4 v1; v1.x = acc[i][4]; v1.y = acc[i][5]; v1.z = acc[i][6]; v1.w = acc[i][7];
    *(float4*)&Xd[(size_t)mi * 4096 + b * 128 + tx * 8] = v0;
    *(float4*)&Xd[(size_t)mi * 4096 + b * 128 + tx * 8 + 4] = v1;
  }
#pragma unroll
  for (int j = 0; j < 8; ++j) {
    int g = b * 128 + tx * 8 + j;
    ushort4 o;
    o.x = f2h(acc[0][j]); o.y = f2h(acc[1][j]);
    o.z = f2h(acc[2][j]); o.w = f2h(acc[3][j]);
    *(ushort4*)&Xf1[(size_t)g * 512 + m0 + ty * 4] = o;
  }
}

// ---------------------------------------------------------------------------
// X2t = cat(x_t, r*h) @ W2 with fused r-gate (reads G1t/X1lo rows 0..255).
// ---------------------------------------------------------------------------
__global__ __launch_bounds__(256) void xw_cat2(
    const float* __restrict__ inp, const float* __restrict__ h,
    const float* __restrict__ W, float* __restrict__ X2t,
    unsigned short* __restrict__ Xf2,
    const float* __restrict__ G1t, const float* __restrict__ X1lo,
    const float* __restrict__ st1, const float* __restrict__ gamma1,
    const float* __restrict__ beta1, const float* __restrict__ bias1,
    int t, float* __restrict__ zptr, int zn) {
  __shared__ float As[80][64];
  __shared__ float Ws[80][64];
  __shared__ float sm[128], sa[128], sb[128], sbb[128];
  const int tid = threadIdx.x;
  const int bid = blockIdx.x;
  const int b = bid >> 3, m0 = (bid & 7) * 64;
  if (bid == 0 && tid < zn) zptr[tid] = 0.f;
  if (tid < 128) {
    float mean = st1[tid] * (1.f / CNT_);
    float var = fmaf(st1[128 + tid], 1.f / CNT_, -mean * mean);
    float inv = rsqrtf(var + EPS_);
    sm[tid] = mean; sa[tid] = inv * gamma1[tid];
    sb[tid] = beta1[tid]; sbb[tid] = bias1[tid];
  }
  __syncthreads();
  for (int i = tid * 4; i < 80 * 64; i += 1024)
    *(float4*)(((float*)Ws) + i) = *(const float4*)&W[i];
  const int rl = tid >> 2;
  const int m = m0 + rl;
  const int k4 = (tid & 3) * 4;
  {
    float4 v = *(const float4*)&inp[(size_t)((b * S_ + t) * N_ + m) * D_ + k4];
    As[k4 + 0][rl] = v.x; As[k4 + 1][rl] = v.y; As[k4 + 2][rl] = v.z; As[k4 + 3][rl] = v.w;
  }
#pragma unroll
  for (int q = 0; q < 4; ++q) {
    int c = (tid & 3) * 16 + q * 4;
    float4 hv = *(const float4*)&h[(size_t)(b * N_ + m) * H_ + c];
    int j0 = m * H_ + c;
    int n = j0 >> 7;           // < 256
    int dd = j0 & 127;
    float4 gv = *(const float4*)&G1t[(size_t)n * 4096 + b * 128 + dd];
    float4 xv = *(const float4*)&X1lo[(size_t)n * 4096 + b * 128 + dd];
    float hva[4] = {hv.x, hv.y, hv.z, hv.w};
    float gva[4] = {gv.x, gv.y, gv.z, gv.w};
    float xva[4] = {xv.x, xv.y, xv.z, xv.w};
#pragma unroll
    for (int i2 = 0; i2 < 4; ++i2) {
      int d2 = dd + i2;
      float pre = fmaf(gva[i2] - sm[d2], sa[d2], sb[d2]);
      pre = fmaxf(pre, 0.f) + xva[i2] + sbb[d2];
      As[16 + c + i2][rl] = sigm(pre) * hva[i2];
    }
  }
  __syncthreads();
  const int tx = tid & 15, ty = tid >> 4;
  float acc[4][4];
#pragma unroll
  for (int i = 0; i < 4; ++i)
#pragma unroll
    for (int j = 0; j < 4; ++j) acc[i][j] = 0.f;
  for (int k = 0; k < 80; ++k) {
    float a[4], bv[4];
#pragma unroll
    for (int i = 0; i < 4; ++i) a[i] = As[k][ty * 4 + i];
#pragma unroll
    for (int j = 0; j < 4; ++j) bv[j] = Ws[k][tx * 4 + j];
#pragma unroll
    for (int i = 0; i < 4; ++i)
#pragma unroll
      for (int j = 0; j < 4; ++j) acc[i][j] = fmaf(a[i], bv[j], acc[i][j]);
  }
#pragma unroll
  for (int i = 0; i < 4; ++i) {
    const int mi = m0 + ty * 4 + i;
    float4 v0; v0.x = acc[i][0]; v0.y = acc[i][1]; v0.z = acc[i][2]; v0.w = acc[i][3];
    *(float4*)&X2t[(size_t)mi * 2048 + b * 64 + tx * 4] = v0;
  }
#pragma unroll
  for (int j = 0; j < 4; ++j) {
    int g = b * 64 + tx * 4 + j;
    ushort4 o;
    o.x = f2h(acc[0][j]); o.y = f2h(acc[1][j]);
    o.z = f2h(acc[2][j]); o.w = f2h(acc[3][j]);
    *(ushort4*)&Xf2[(size_t)g * 512 + m0 + ty * 4] = o;
  }
}

// ---------------------------------------------------------------------------
// FUSED: h-update + [bwd] feats1 write + [fwd] out-layer stage1 + feats0
// overwrite + X1 projection for the NEXT timestep.
// Phase E reads X1hiC; phase X writes X1lo (read only by NEXT dispatch) and
// X1hiN (ping-pong partner). out1 layout: b*SNH_ + t*NH_ + m*64 + c.
// mode bits: 1 = write feats1 ; 2 = out-layer ; 4 = do X1(nextT).
// ---------------------------------------------------------------------------
__global__ __launch_bounds__(512) void eltxw1(
    const float* __restrict__ inp,
    const float* __restrict__ G1t, const float* __restrict__ X1hiC,
    const float* __restrict__ st1, const float* __restrict__ gamma1,
    const float* __restrict__ beta1, const float* __restrict__ bias1,
    const float* __restrict__ G2t, const float* __restrict__ X2t,
    const float* __restrict__ st2, const float* __restrict__ gamma2,
    const float* __restrict__ beta2, const float* __restrict__ bias2,
    float* __restrict__ h, float* __restrict__ out1,
    const float* __restrict__ W1, float* __restrict__ X1lo,
    float* __restrict__ X1hiN, unsigned short* __restrict__ Xf1,
    const float* __restrict__ W0o, const float* __restrict__ W1o,
    float* __restrict__ Xot,
    int t, int nextT, int mode,
    float* __restrict__ z1, float* __restrict__ zo) {
  __shared__ float As[64][80];      // [row][k]: k<16 = x_next, k>=16 = hn
  __shared__ float Ws[80][128];
  __shared__ float sW0[128], sW1[128];
  const int tid = threadIdx.x;
  const int b = blockIdx.x >> 3, m0 = (blockIdx.x & 7) * 64;
  const bool doFeats = (mode & 1) != 0;
  const bool doOut = (mode & 2) != 0;
  const bool doX1 = (mode & 4) != 0;
  if (blockIdx.x == 0) {
    if (tid < 256) z1[tid] = 0.f;
    else if (tid < 264) zo[tid - 256] = 0.f;
  }
  if (tid < 128) { sW0[tid] = W0o[tid]; sW1[tid] = W1o[tid]; }
  __syncthreads();

  // ---- phase E: gates + h update for (row, co..co+7) ----
  const int row = tid >> 3, co = (tid & 7) * 8;
  const int m = m0 + row;
  const int mh = m >> 1;                    // X1hi row (nu - 256)
  const int du0 = ((m & 1) << 6) + co;
  const size_t o1idx = (size_t)b * SNH_ + (size_t)t * NH_ + m * 64 + co;
  float g1a[8], x1a[8], g2a[8], x2a[8], ha[8], f1a[8];
  {
    const float* p1 = &G1t[(size_t)(256 + mh) * 4096 + b * 128 + du0];
    const float* p2 = &X1hiC[(size_t)mh * 4096 + b * 128 + du0];
    const float* p3 = &G2t[(size_t)m * 2048 + b * 64 + co];
    const float* p4 = &X2t[(size_t)m * 2048 + b * 64 + co];
    const float* p5 = &h[(size_t)b * 32768 + m * 64 + co];
    *(float4*)&g1a[0] = *(const float4*)&p1[0];
    *(float4*)&g1a[4] = *(const float4*)&p1[4];
    *(float4*)&x1a[0] = *(const float4*)&p2[0];
    *(float4*)&x1a[4] = *(const float4*)&p2[4];
    *(float4*)&g2a[0] = *(const float4*)&p3[0];
    *(float4*)&g2a[4] = *(const float4*)&p3[4];
    *(float4*)&x2a[0] = *(const float4*)&p4[0];
    *(float4*)&x2a[4] = *(const float4*)&p4[4];
    *(float4*)&ha[0] = *(const float4*)&p5[0];
    *(float4*)&ha[4] = *(const float4*)&p5[4];
  }
  if (doOut) {
    *(float4*)&f1a[0] = *(const float4*)&out1[o1idx];
    *(float4*)&f1a[4] = *(const float4*)&out1[o1idx + 4];
  }
  float hn[8];
#pragma unroll
  for (int i = 0; i < 8; ++i) {
    int du = du0 + i;
    float mean = st1[du] * (1.f / CNT_);
    float var = st1[128 + du] * (1.f / CNT_) - mean * mean;
    float inv = rsqrtf(var + EPS_);
    float pre = fmaxf((g1a[i] - mean) * inv * gamma1[du] + beta1[du], 0.f) + x1a[i] + bias1[du];
    float u = sigm(pre);
    int dc = co + i;
    float mean2 = st2[dc] * (1.f / CNT_);
    float var2 = st2[64 + dc] * (1.f / CNT_) - mean2 * mean2;
    float inv2 = rsqrtf(var2 + EPS_);
    float pre2 = fmaxf((g2a[i] - mean2) * inv2 * gamma2[dc] + beta2[dc], 0.f) + x2a[i] + bias2[dc];
    float cc = tanhf(pre2);
    hn[i] = u * ha[i] + (1.f - u) * cc;
  }
  {
    float* ph = &h[(size_t)b * 32768 + m * 64 + co];
    *(float4*)&ph[0] = *(const float4*)&hn[0];
    *(float4*)&ph[4] = *(const float4*)&hn[4];
  }
  *(float4*)&As[row][16 + co] = *(const float4*)&hn[0];
  *(float4*)&As[row][16 + co + 4] = *(const float4*)&hn[4];
  if (doFeats || doOut) {  // bwd: feats1; fwd: feats0 (after f1 read above)
    *(float4*)&out1[o1idx] = *(const float4*)&hn[0];
    *(float4*)&out1[o1idx + 4] = *(const float4*)&hn[4];
  }
  if (doOut) {
    float p00 = 0.f, p01 = 0.f, p10 = 0.f, p11 = 0.f;
#pragma unroll
    for (int j = 0; j < 8; ++j) {
      int c = co + j;
      p00 = fmaf(hn[j], sW0[c * 2], p00);
      p01 = fmaf(hn[j], sW0[c * 2 + 1], p01);
      p10 = fmaf(f1a[j], sW1[c * 2], p10);
      p11 = fmaf(f1a[j], sW1[c * 2 + 1], p11);
    }
#pragma unroll
    for (int off = 1; off < 8; off <<= 1) {
      p00 += __shfl_xor(p00, off);
      p01 += __shfl_xor(p01, off);
      p10 += __shfl_xor(p10, off);
      p11 += __shfl_xor(p11, off);
    }
    if ((tid & 7) == 0) {
      Xot[m * 128 + b * 2 + 0] = p00;
      Xot[m * 128 + b * 2 + 1] = p01;
      Xot[m * 128 + 64 + b * 2 + 0] = p10;
      Xot[m * 128 + 64 + b * 2 + 1] = p11;
    }
  }

  // ---- phase X: X1(nextT) = cat(x_next, hn) @ W1 ----
  if (doX1) {
    {
      int ri = tid >> 3, k2 = (tid & 7) * 2;
      float2 iv = *(const float2*)&inp[(size_t)((b * S_ + nextT) * N_ + m0 + ri) * D_ + k2];
      As[ri][k2] = iv.x;
      As[ri][k2 + 1] = iv.y;
    }
    float* wsf = &Ws[0][0];
    for (int i = tid * 4; i < 80 * 128; i += 2048)
      *(float4*)&wsf[i] = *(const float4*)&W1[i];
    __syncthreads();
    const int tx = tid & 31, ty = tid >> 5;
    float acc[4][4];
#pragma unroll
    for (int i = 0; i < 4; ++i)
#pragma unroll
      for (int j = 0; j < 4; ++j) acc[i][j] = 0.f;
    for (int k = 0; k < 80; ++k) {
      float a[4], bv[4];
#pragma unroll
      for (int i = 0; i < 4; ++i) a[i] = As[ty * 4 + i][k];
#pragma unroll
      for (int j = 0; j < 4; ++j) bv[j] = Ws[k][tx * 4 + j];
#pragma unroll
      for (int i = 0; i < 4; ++i)
#pragma unroll
        for (int j = 0; j < 4; ++j) acc[i][j] = fmaf(a[i], bv[j], acc[i][j]);
    }
    float* Xd = (m0 < 256) ? X1lo : X1hiN;
    const int mb = (m0 < 256) ? m0 : (m0 - 256);
#pragma unroll
    for (int i = 0; i < 4; ++i) {
      float4 v; v.x = acc[i][0]; v.y = acc[i][1]; v.z = acc[i][2]; v.w = acc[i][3];
      *(float4*)&Xd[(size_t)(mb + ty * 4 + i) * 4096 + b * 128 + tx * 4] = v;
    }
#pragma unroll
    for (int j = 0; j < 4; ++j) {
      int g = b * 128 + tx * 4 + j;
      ushort4 o;
      o.x = f2h(acc[0][j]); o.y = f2h(acc[1][j]);
      o.z = f2h(acc[2][j]); o.w = f2h(acc[3][j]);
      *(ushort4*)&Xf1[(size_t)g * 512 + m0 + ty * 4] = o;
    }
  }
}

__global__ __launch_bounds__(256) void outfinalk(
    const float* __restrict__ Got, const float* __restrict__ Xot, const float* __restrict__ sto,
    const float* __restrict__ gammao, const float* __restrict__ betao, const float* __restrict__ bo,
    float* __restrict__ out0, int t) {
  const int idx = blockIdx.x * 256 + threadIdx.x;
  const int b = idx >> 9, n = idx & 511;
  float pr[2];
#pragma unroll
  for (int p = 0; p < 2; ++p) {
    float h0 = Xot[n * 128 + b * 2 + p];
    float go0 = Got[n * 128 + b * 2 + p];
    float h1 = Xot[n * 128 + 64 + b * 2 + p];
    float go1 = Got[n * 128 + 64 + b * 2 + p];
    float mean0 = sto[p] * (1.f / CNT_);
    float var0 = sto[4 + p] * (1.f / CNT_) - mean0 * mean0;
    float inv0 = rsqrtf(var0 + EPS_);
    float mean1 = sto[2 + p] * (1.f / CNT_);
    float var1 = sto[6 + p] * (1.f / CNT_) - mean1 * mean1;
    float inv1 = rsqrtf(var1 + EPS_);
    float o0 = fmaxf((go0 - mean0) * inv0 * gammao[p] + betao[p], 0.f) + h0;
    float o1 = fmaxf((go1 - mean1) * inv1 * gammao[p] + betao[p], 0.f) + h1;
    pr[p] = 0.5f * (o0 + o1) + bo[p];
  }
  float2 v; v.x = pr[0]; v.y = pr[1];
  *(float2*)&out0[(size_t)((b * S_ + t) * N_ + n) * 2] = v;
}

// ---------------------------------------------------------------------------
extern "C" void kernel_launch(void* const* d_in, const int* in_sizes, int n_in,
                              void* d_out, int out_size, void* d_ws, size_t ws_size,
                              hipStream_t stream) {
  (void)in_sizes; (void)n_in; (void)out_size; (void)ws_size;
  const float* inp = (const float*)d_in[0];
  const float* inc = (const float*)d_in[1];
  const float* W1 = (const float*)d_in[2];
  const float* b1 = (const float*)d_in[3];
  const float* g1 = (const float*)d_in[4];
  const float* e1 = (const float*)d_in[5];
  const float* W2 = (const float*)d_in[6];
  const float* b2 = (const float*)d_in[7];
  const float* g2 = (const float*)d_in[8];
  const float* e2 = (const float*)d_in[9];
  const float* W0o = (const float*)d_in[10];
  const float* W1o = (const float*)d_in[11];
  const float* bo = (const float*)d_in[12];
  const float* go = (const float*)d_in[13];
  const float* eo = (const float*)d_in[14];

  // workspace layout (floats); ~10.6M floats ~42.5 MB
  float* ws = (float*)d_ws;
  float* G     = ws;                   // 512*512
  float* Hs    = G + 262144;           // 512*128
  float* Hd    = Hs + 65536;           // 512*128
  float* h     = Hd + 65536;           // 1048576
  float* X1lo  = h + 1048576;          // 256*4096
  float* X1hiA = X1lo + 1048576;       // 256*4096
  float* X1hiB = X1hiA + 1048576;      // 256*4096
  float* G1t   = X1hiB + 1048576;      // 512*4096
  float* X2t   = G1t + 2097152;        // 512*2048
  float* G2t   = X2t + 1048576;        // 512*2048
  float* Xot   = G2t + 1048576;        // 512*128
  float* Got   = Xot + 65536;          // 512*128
  float* st1a  = Got + 65536;          // 256
  float* st1b  = st1a + 256;           // 256
  float* st2   = st1b + 256;           // 128
  float* sto   = st2 + 128;            // 8 (stats pad to 1024)
  float* after = st1a + 1024;
  unsigned short* Gh  = (unsigned short*)after;             // 512*512 fp16
  unsigned short* Xf1 = (unsigned short*)(after + 131072);  // 4096*512 fp16
  unsigned short* Xf2 = (unsigned short*)(after + 131072 + 1048576); // 2048*512

  float* out0 = (float*)d_out;
  float* out1 = out0 + (size_t)B_ * S_ * N_ * 2;

  // Build G = Hd @ Hs^T once; fp16 copy
  k_deg<<<1, 256, 0, stream>>>(inc, Hs, Hd);
  gemmk<64, 64, 4, 4, 0, true><<<dim3(8, 8), 256, 0, stream>>>(
      Hd, Hs, G, 512, 512, 128, 0, nullptr, 0, nullptr, 0);
  g2h<<<256, 256, 0, stream>>>(G, Gh);

  for (int dir = 0; dir < 2; ++dir) {
    hipMemsetAsync(h, 0, (size_t)1048576 * sizeof(float), stream);
    {
      const int t0 = dir ? 0 : (S_ - 1);
      xw_cat1<<<256, 256, 0, stream>>>(inp, h, W1, X1lo, X1hiA, Xf1, t0, st1a, 256);
    }
    for (int ti = 0; ti < S_; ++ti) {
      const int t = dir ? ti : (S_ - 1 - ti);
      const int nextT = dir ? (t + 1) : (t - 1);
      float* stc = (ti & 1) ? st1b : st1a;
      float* stn = (ti & 1) ? st1a : st1b;
      float* x1hiC = (ti & 1) ? X1hiB : X1hiA;
      float* x1hiN = (ti & 1) ? X1hiA : X1hiB;
      const int last = (ti == S_ - 1);
      const int mode = (dir ? 2 : 1) | (last ? 0 : 4);

      gmfma<<<dim3(64, 4), 256, 0, stream>>>(Gh, Xf1, G1t, 4096, 127, stc, 128);
      xw_cat2<<<256, 256, 0, stream>>>(inp, h, W2, X2t, Xf2, G1t, X1lo, stc, g1,
                                       e1, b1, t, st2, 128);
      gmfma<<<dim3(32, 4), 256, 0, stream>>>(Gh, Xf2, G2t, 2048, 63, st2, 64);
      eltxw1<<<256, 512, 0, stream>>>(inp, G1t, x1hiC, stc, g1, e1, b1, G2t, X2t,
                                      st2, g2, e2, b2, h, out1, W1, X1lo, x1hiN,
                                      Xf1, W0o, W1o, Xot, t, last ? 0 : nextT,
                                      mode, stn, sto);
      if (dir == 1) {
        gemmk<32, 32, 2, 2, 2, false><<<dim3(4, 16), 256, 0, stream>>>(
            G, Xot, Got, 512, 128, 512, 0, sto, 4, nullptr, 0);
        outfinalk<<<64, 256, 0, stream>>>(Got, Xot, sto, go, eo, bo, out0, t);
      }
    }
  }
}